// Round 1
// 560.165 us; speedup vs baseline: 1.0595x; 1.0595x over previous
//
#include <hip/hip_runtime.h>
#include <hip/hip_bf16.h>
#include <cmath>

#define NROWS 8192
#define DIM   128
#define KDIM  8192
#define BM    64
#define BN    128
#define BK    64
#define SPLITK 4
#define KCHUNK (KDIM / SPLITK)   // 2048
#define GITERS (KCHUNK / BK)     // 32
#define MTILES (NROWS / BM)      // 128
#define KBLKS  (KDIM / BK)       // 128
#define NBUF   3                 // 3-deep LDS pipeline (72 KB -> 2 blocks/CU)
#define LDSTRIDE 80              // proj kernel only

typedef __bf16 bf16_t;
typedef __bf16 bf16x8 __attribute__((ext_vector_type(8)));
typedef float  f32x4  __attribute__((ext_vector_type(4)));

// DMA-image layout for staged operands:
//   img16[(rg * KBLKS + kblk) * 64 + lane]  (16 B units)
// where rg = row/8, lane = lrow*8 + p (lrow = row%8), and position p holds
// the 8-element k-chunk c = p ^ lrow of global k-block kblk. A wave-level
// global_load_lds of 1 KB (lane-ordered, contiguous) then lands the XOR-
// swizzled LDS tile directly; MFMA frag reads use csX = chunk ^ (row&7).

__device__ __forceinline__ void async16(const void* g, void* l) {
    __builtin_amdgcn_global_load_lds(
        (const __attribute__((address_space(1))) unsigned int*)g,
        (__attribute__((address_space(3))) unsigned int*)l, 16, 0, 0);
}

// ------------- theta: transpose to [k][o][i], scale by c_k, bf16 ------------
__global__ void k_theta(const float* __restrict__ th, bf16_t* __restrict__ out,
                        float c0, float c1, float c2, float c3, float c4) {
    int idx = blockIdx.x * 256 + threadIdx.x;          // 81920 total
    int k = idx >> 14;
    int o = (idx >> 7) & 127;
    int i = idx & 127;
    float c = (k == 0) ? c0 : (k == 1) ? c1 : (k == 2) ? c2 : (k == 3) ? c3 : c4;
    out[idx] = (bf16_t)(c * th[(k << 14) + (i << 7) + o]);
}

// ---- convert: fp32 L (row-major) -> bf16 Lbf in DMA-image layout -----------
// Pure streaming (reads 268 MB, writes 134 MB); replaces the old fused
// MODE-2 GEMM so all 4 GEMMs run the pipelined image path.
__global__ __launch_bounds__(256)
void k_convert(const float* __restrict__ L, bf16_t* __restrict__ Lbf) {
    const int lane = threadIdx.x & 63;
    const int lrow = lane >> 3;
    const int p    = lane & 7;
    const int c    = p ^ lrow;            // global k-chunk this lane carries
    const int nWaves = gridDim.x * 4;
    const int TOT = (NROWS / 8) * KBLKS;  // 131072 wave-tasks
    for (int w = blockIdx.x * 4 + (threadIdx.x >> 6); w < TOT; w += nWaves) {
        const int rg   = w >> 7;          // KBLKS = 128
        const int kblk = w & (KBLKS - 1);
        const int row  = rg * 8 + lrow;
        const float* src = L + (size_t)row * KDIM + kblk * 64 + c * 8;
        float4 a = *(const float4*)src;
        float4 b = *(const float4*)(src + 4);
        bf16x8 v;
        v[0] = (bf16_t)a.x; v[1] = (bf16_t)a.y; v[2] = (bf16_t)a.z; v[3] = (bf16_t)a.w;
        v[4] = (bf16_t)b.x; v[5] = (bf16_t)b.y; v[6] = (bf16_t)b.z; v[7] = (bf16_t)b.w;
        *(bf16x8*)(Lbf + (((size_t)rg * KBLKS + kblk) * 64 + lane) * 8) = v;
    }
}

// --------- GEMM: partial[s] = L[:, chunk_s] @ T_chunk ----------------------
// 3-buffer global_load_lds pipeline with counted vmcnt (T3+T4): tiles kk+1
// and kk+2 stay in flight across the barriers; only the 2 newest tiles
// (12 loads/wave) may be outstanding when compute(kk) starts.
__global__ __launch_bounds__(256, 2)
void k_gemm(const bf16_t* __restrict__ A, const bf16_t* __restrict__ Bt,
            float* __restrict__ partial) {
    __shared__ __align__(16) bf16_t As[NBUF][BM * BK];   // 3 x 8 KB
    __shared__ __align__(16) bf16_t Bs[NBUF][BN * BK];   // 3 x 16 KB

    const int t     = threadIdx.x;
    const int mTile = blockIdx.x & (MTILES - 1);
    const int s     = blockIdx.x >> 7;
    const int mb    = mTile * BM;
    const int sKB   = s * (KCHUNK / BK);   // first k-block of this chunk
    const int rgA   = mb >> 3;             // first row-group of A tile
    const int wave = t >> 6, lane = t & 63;
    const int wM = (wave & 1) * 32;
    const int wN = (wave >> 1) * 64;
    const int lm = lane & 15, lk = lane >> 4;

    f32x4 acc[2][4];
#pragma unroll
    for (int a = 0; a < 2; ++a)
#pragma unroll
        for (int b = 0; b < 4; ++b) acc[a][b] = (f32x4)0.0f;

    // 6 global_load_lds per wave per tile: A 2x1KB + B 4x1KB
    auto stage = [&](int kk, int buf) {
        const int kblk = sKB + kk;
#pragma unroll
        for (int j = 0; j < 2; ++j) {
            const int rg = rgA + wave * 2 + j;
            async16(A + (((size_t)rg * KBLKS + kblk) * 64 + lane) * 8,
                    &As[buf][(wave * 16 + j * 8) * BK]);
        }
#pragma unroll
        for (int i = 0; i < 4; ++i) {
            const int fg = wave * 4 + i;
            async16(Bt + (((size_t)fg * KBLKS + kblk) * 64 + lane) * 8,
                    &Bs[buf][(wave * 32 + i * 8) * BK]);
        }
    };

    auto compute = [&](int buf) {
#pragma unroll
        for (int ko = 0; ko < 2; ++ko) {
            const int csX = (ko * 4 + lk) ^ (lm & 7);
            bf16x8 af[2], bfr[4];
#pragma unroll
            for (int tm = 0; tm < 2; ++tm)
                af[tm] = *(const bf16x8*)(&As[buf][(wM + tm * 16 + lm) * BK + csX * 8]);
#pragma unroll
            for (int tn = 0; tn < 4; ++tn)
                bfr[tn] = *(const bf16x8*)(&Bs[buf][(wN + tn * 16 + lm) * BK + csX * 8]);
            __builtin_amdgcn_s_setprio(1);
#pragma unroll
            for (int tm = 0; tm < 2; ++tm)
#pragma unroll
                for (int tn = 0; tn < 4; ++tn)
                    acc[tm][tn] = __builtin_amdgcn_mfma_f32_16x16x32_bf16(
                        af[tm], bfr[tn], acc[tm][tn], 0, 0, 0);
            __builtin_amdgcn_s_setprio(0);
        }
    };

    // Prologue: fill all 3 buffers (18 loads/wave in flight).
    stage(0, 0); stage(1, 1); stage(2, 2);

    for (int kk = 0; kk < GITERS - 2; ++kk) {
        const int buf = kk % NBUF;
        // Wait own tile-kk loads (newest 12 = tiles kk+1, kk+2 may remain).
        asm volatile("s_waitcnt vmcnt(12)" ::: "memory");
        __builtin_amdgcn_s_barrier();              // all waves: tile kk landed
        __builtin_amdgcn_sched_barrier(0);         // no ds_read hoists above
        compute(buf);
        __builtin_amdgcn_sched_barrier(0);
        __builtin_amdgcn_s_barrier();              // all waves done reading buf
        if (kk < GITERS - 3) stage(kk + 3, buf);   // refill freed buffer
    }
    // Peeled tail: kk = GITERS-2 (one tile still in flight), kk = GITERS-1.
    asm volatile("s_waitcnt vmcnt(6)" ::: "memory");
    __builtin_amdgcn_s_barrier();
    __builtin_amdgcn_sched_barrier(0);
    compute((GITERS - 2) % NBUF);
    asm volatile("s_waitcnt vmcnt(0)" ::: "memory");
    __builtin_amdgcn_s_barrier();
    __builtin_amdgcn_sched_barrier(0);
    compute((GITERS - 1) % NBUF);

    float* pOut = partial + (size_t)s * NROWS * DIM;
#pragma unroll
    for (int tm = 0; tm < 2; ++tm)
#pragma unroll
        for (int tn = 0; tn < 4; ++tn)
#pragma unroll
            for (int r = 0; r < 4; ++r) {
                const int row = mb + wM + tm * 16 + lk * 4 + r;
                const int col = wN + tn * 16 + lm;
                pOut[(size_t)row * DIM + col] = acc[tm][tn][r];
            }
}

// ---- combine: y = sum(partials) [or x]; recurrence; emit fp32/Tbf/Bt -------
// MODE 0: y = src (fp32 x).  MODE 1: y = sum_s partial.  MODE 2: 2*sum - prev.
// bt output is written in the gemm's DMA-image layout.
template <int MODE>
__global__ void k_combine(const float* __restrict__ src, const float* __restrict__ prev,
                          float* __restrict__ f32dst, bf16_t* __restrict__ tbf,
                          bf16_t* __restrict__ bt) {
    __shared__ bf16_t tl[128 * 24];      // [feat][16 node + pad]
    const size_t S = (size_t)NROWS * DIM;
    const int t  = threadIdx.x;
    const int n0 = blockIdx.x * 16;
    const int nl = t >> 4;               // 0..15 node within tile
    const int dp = (t & 15) * 8;         // 0..120 feature offset
    const int n  = n0 + nl;

    float y[8];
    if (MODE == 0) {
        float4 a = *(const float4*)(src + (size_t)n * DIM + dp);
        float4 b = *(const float4*)(src + (size_t)n * DIM + dp + 4);
        y[0] = a.x; y[1] = a.y; y[2] = a.z; y[3] = a.w;
        y[4] = b.x; y[5] = b.y; y[6] = b.z; y[7] = b.w;
    } else {
#pragma unroll
        for (int j = 0; j < 8; ++j) y[j] = 0.0f;
#pragma unroll
        for (int ss = 0; ss < SPLITK; ++ss) {
            const float* p = src + (size_t)ss * S + (size_t)n * DIM + dp;
            float4 a = *(const float4*)p;
            float4 b = *(const float4*)(p + 4);
            y[0] += a.x; y[1] += a.y; y[2] += a.z; y[3] += a.w;
            y[4] += b.x; y[5] += b.y; y[6] += b.z; y[7] += b.w;
        }
        if (MODE == 2) {
            float4 a = *(const float4*)(prev + (size_t)n * DIM + dp);
            float4 b = *(const float4*)(prev + (size_t)n * DIM + dp + 4);
            y[0] = 2.0f * y[0] - a.x; y[1] = 2.0f * y[1] - a.y;
            y[2] = 2.0f * y[2] - a.z; y[3] = 2.0f * y[3] - a.w;
            y[4] = 2.0f * y[4] - b.x; y[5] = 2.0f * y[5] - b.y;
            y[6] = 2.0f * y[6] - b.z; y[7] = 2.0f * y[7] - b.w;
        }
    }
    if (f32dst) {
        float4 a, b;
        a.x = y[0]; a.y = y[1]; a.z = y[2]; a.w = y[3];
        b.x = y[4]; b.y = y[5]; b.z = y[6]; b.w = y[7];
        *(float4*)(f32dst + (size_t)n * DIM + dp) = a;
        *(float4*)(f32dst + (size_t)n * DIM + dp + 4) = b;
    }
    bf16x8 v;
#pragma unroll
    for (int j = 0; j < 8; ++j) v[j] = (bf16_t)y[j];
    *(bf16x8*)(tbf + (size_t)n * DIM + dp) = v;
    if (bt) {
#pragma unroll
        for (int j = 0; j < 8; ++j) tl[(dp + j) * 24 + nl] = v[j];
        __syncthreads();
        const int d = t >> 1;                 // feat 0..127
        const int h = (t & 1) * 8;            // node sub-offset 0/8
        bf16x8 w = *(const bf16x8*)(&tl[d * 24 + h]);
        const int c    = ((n0 + h) >> 3) & 7; // k-chunk within k-block
        const int lane = (d & 7) * 8 + (c ^ (d & 7));
        const size_t a16 = ((size_t)(d >> 3) * KBLKS + (n0 >> 6)) * 64 + lane;
        *(bf16x8*)(bt + a16 * 8) = w;
    }
}

// ------- projection: out = sum_seg Tbf[seg] @ thT[seg]^T (c_k pre-folded) ----
__global__ __launch_bounds__(256, 2)
void k_proj(const bf16_t* __restrict__ T, const bf16_t* __restrict__ W,
            float* __restrict__ out) {
    __shared__ __align__(16) bf16_t As[64 * LDSTRIDE];
    __shared__ __align__(16) bf16_t Bs[128 * LDSTRIDE];

    const int t  = threadIdx.x;
    const int mb = blockIdx.x * 64;
    const int wave = t >> 6, lane = t & 63;
    const int wM = (wave & 1) * 32;
    const int wN = (wave >> 1) * 64;
    const int lm = lane & 15, lk = lane >> 4;
    const int arow = t >> 3;
    const int asc  = t & 7;
    const size_t S = (size_t)NROWS * DIM;

    f32x4 acc[2][4];
#pragma unroll
    for (int a = 0; a < 2; ++a)
#pragma unroll
        for (int b = 0; b < 4; ++b) acc[a][b] = (f32x4)0.0f;

    bf16x8 aR[2], bR[4];

    auto loadT = [&](int it) {
        const int seg = it >> 1;
        const int h   = (it & 1) * 64;
#pragma unroll
        for (int rep = 0; rep < 2; ++rep) {
            const int r = rep * 32 + arow;
            aR[rep] = *(const bf16x8*)(T + (size_t)seg * S +
                        (size_t)(mb + r) * DIM + h + asc * 8);
        }
#pragma unroll
        for (int rep = 0; rep < 4; ++rep) {
            const int o = rep * 32 + arow;
            bR[rep] = *(const bf16x8*)(W + seg * 16384 + o * 128 + h + asc * 8);
        }
    };
    auto storeT = [&]() {
#pragma unroll
        for (int rep = 0; rep < 2; ++rep) {
            const int r = rep * 32 + arow;
            *(bf16x8*)(&As[r * LDSTRIDE + asc * 8]) = aR[rep];
        }
#pragma unroll
        for (int rep = 0; rep < 4; ++rep) {
            const int o = rep * 32 + arow;
            *(bf16x8*)(&Bs[o * LDSTRIDE + asc * 8]) = bR[rep];
        }
    };

    loadT(0);
    for (int it = 0; it < 10; ++it) {
        __syncthreads();
        storeT();
        __syncthreads();
        if (it + 1 < 10) loadT(it + 1);
#pragma unroll
        for (int ko = 0; ko < 2; ++ko) {
            bf16x8 af[2], bfr[4];
#pragma unroll
            for (int tm = 0; tm < 2; ++tm)
                af[tm] = *(const bf16x8*)(&As[(wM + tm * 16 + lm) * LDSTRIDE +
                                              (ko * 4 + lk) * 8]);
#pragma unroll
            for (int tn = 0; tn < 4; ++tn)
                bfr[tn] = *(const bf16x8*)(&Bs[(wN + tn * 16 + lm) * LDSTRIDE +
                                               (ko * 4 + lk) * 8]);
#pragma unroll
            for (int tm = 0; tm < 2; ++tm)
#pragma unroll
                for (int tn = 0; tn < 4; ++tn)
                    acc[tm][tn] = __builtin_amdgcn_mfma_f32_16x16x32_bf16(
                        af[tm], bfr[tn], acc[tm][tn], 0, 0, 0);
        }
    }
#pragma unroll
    for (int tm = 0; tm < 2; ++tm)
#pragma unroll
        for (int tn = 0; tn < 4; ++tn)
#pragma unroll
            for (int r = 0; r < 4; ++r) {
                const int row = mb + wM + tm * 16 + lk * 4 + r;
                const int col = wN + tn * 16 + lm;
                out[(size_t)row * DIM + col] = acc[tm][tn][r];
            }
}

extern "C" void kernel_launch(void* const* d_in, const int* in_sizes, int n_in,
                              void* d_out, int out_size, void* d_ws, size_t ws_size,
                              hipStream_t stream) {
    const float* x  = nullptr;
    const float* L  = nullptr;
    const float* th = nullptr;
    for (int i = 0; i < n_in; ++i) {
        if (in_sizes[i] == NROWS * KDIM)       L  = (const float*)d_in[i];
        else if (in_sizes[i] == NROWS * DIM)   x  = (const float*)d_in[i];
        else if (in_sizes[i] == 5 * DIM * DIM) th = (const float*)d_in[i];
    }
    float* out = (float*)d_out;

    const size_t S = (size_t)NROWS * DIM;          // 1048576 elems
    char* ws = (char*)d_ws;
    size_t off = 0;
    auto alloc = [&](size_t bytes) {
        void* p = ws + off;
        off = (off + bytes + 255) & ~(size_t)255;
        return p;
    };
    bf16_t* Tbf     = (bf16_t*)alloc(5 * S * 2);        // [5][node][feat]
    bf16_t* Bt      = (bf16_t*)alloc(5 * S * 2);        // [5] DMA-image
    float*  Tf32    = (float*)alloc(2 * S * 4);         // fp32 recurrence state
    bf16_t* thT     = (bf16_t*)alloc(5 * 128 * 128 * 2);
    float*  partial = (float*)alloc((size_t)SPLITK * S * 4);
    bf16_t* Lbf     = (bf16_t*)alloc((size_t)NROWS * KDIM * 2);  // DMA-image
    if (off > ws_size) return;

    float c[5];
    for (int k = 0; k < 5; ++k)
        c[k] = (float)((2.0 / 5.0) * exp(-0.5 * cos(M_PI * (k + 0.5) / 5.0)));

    dim3 blk(256);
    k_theta<<<320, blk, 0, stream>>>(th, thT, c[0], c[1], c[2], c[3], c[4]);
    k_convert<<<2048, blk, 0, stream>>>(L, Lbf);
    k_combine<0><<<512, blk, 0, stream>>>(x, nullptr, nullptr, Tbf, Bt);

    for (int j = 1; j <= 4; ++j) {
        const bf16_t* Bj = Bt + (size_t)(j - 1) * S;
        k_gemm<<<MTILES * SPLITK, blk, 0, stream>>>(Lbf, Bj, partial);
        bf16_t* tbf = Tbf + (size_t)j * S;
        bf16_t* bt  = (j < 4) ? Bt + (size_t)j * S : nullptr;
        if (j == 1)
            k_combine<1><<<512, blk, 0, stream>>>(partial, nullptr, Tf32 + S, tbf, bt);
        else if (j == 2)
            k_combine<2><<<512, blk, 0, stream>>>(partial, x, Tf32, tbf, bt);
        else if (j == 3)
            k_combine<2><<<512, blk, 0, stream>>>(partial, Tf32 + S, Tf32 + S, tbf, bt);
        else
            k_combine<2><<<512, blk, 0, stream>>>(partial, Tf32, nullptr, tbf, nullptr);
    }
    k_proj<<<128, blk, 0, stream>>>(Tbf, thT, out);
}